// Round 6
// baseline (167.832 us; speedup 1.0000x reference)
//
#include <hip/hip_runtime.h>

#define RES 1024
#define NROOMS 8
#define NBUCKETS 256                 // 4 grid rows per bucket
#define BINS_PER_BUCKET (4 * RES)    // 4096 bins
#define SWPB 8                       // waves per scatter block (512 threads)
#define NBLK 512                     // exactly 2 blocks/CU
#define F4PT 10                      // max float4 per thread (ceil(2.5M/512/512))
#define STG_MAX (512 * F4PT * 2)     // 10240 entries staged per block (20 KB)

typedef unsigned int u32x4 __attribute__((ext_vector_type(4)));
typedef float        f32x4 __attribute__((ext_vector_type(4)));

// ---------------------------------------------------------------------------
// Device helper: compute one grid cell (4 columns) of all 8 dyn planes.
// NT stores: dyn (32 MB) is never re-read; keep it out of L2.
// ---------------------------------------------------------------------------
__device__ __forceinline__ void dyn_cell(
    const float* __restrict__ room_params,
    const float4* __restrict__ wall,
    float4* __restrict__ dyn, int idx)
{
    int i  = idx >> 8;
    int j0 = (idx & 255) << 2;
    const float inv1023 = 1.0f / 1023.0f;
    float x  = (float)i * inv1023;
    float y0 = (float)(j0 + 0) * inv1023;
    float y1 = (float)(j0 + 1) * inv1023;
    float y2 = (float)(j0 + 2) * inv1023;
    float y3 = (float)(j0 + 3) * inv1023;

    float4 w = wall[idx];
    float omx = 1.0f - w.x;
    float omy = 1.0f - w.y;
    float omz = 1.0f - w.z;
    float omw = 1.0f - w.w;

    const int plane4 = (RES * RES) / 4;
    #pragma unroll
    for (int r = 0; r < NROOMS; ++r) {
        float cx = room_params[4 * r + 0];
        float cy = room_params[4 * r + 1];
        float sx = room_params[4 * r + 2];
        float sy = room_params[4 * r + 3];
        float isx = 1.0f / (2.0f * sx * sx);
        float isy = 1.0f / (2.0f * sy * sy);
        float dx = x - cx;
        float ax = dx * dx * isx;
        float d0 = y0 - cy, d1 = y1 - cy, d2 = y2 - cy, d3 = y3 - cy;
        f32x4 d;
        d.x = __expf(-(ax + d0 * d0 * isy)) * omx;
        d.y = __expf(-(ax + d1 * d1 * isy)) * omy;
        d.z = __expf(-(ax + d2 * d2 * isy)) * omz;
        d.w = __expf(-(ax + d3 * d3 * isy)) * omw;
        __builtin_nontemporal_store(
            d, reinterpret_cast<f32x4*>(&dyn[(size_t)r * plane4 + idx]));
    }
}

// ---------------------------------------------------------------------------
// Pass 1: round-3 scatter structure (LDS code parking, dyn fused mid-kernel)
// with round-5 deltas:
//   * NO cursor / NO global reservation atomics / NO CAP checks:
//     deterministic layout — block B owns buf[B*STG_MAX .. ), writes its
//     bucket-sorted staged data contiguously, and publishes its per-bucket
//     exclusive prefix in meta[B*256+b] (u16, coalesced store).
//   * Phase D is a plain contiguous u32 copy (vector stores, all lanes hot)
//     instead of 32 serialized per-bucket loops.
//   * Block 0 zeroes maxp/done (replaces the hipMemsetAsync dispatch;
//     stream order guarantees visibility to pass 2).
// ---------------------------------------------------------------------------
__global__ __launch_bounds__(512, 4) void scatter_kernel(
    const float4* __restrict__ pos, int n4, int nagents,
    unsigned short* __restrict__ buf, unsigned short* __restrict__ meta,
    unsigned int* __restrict__ maxp, unsigned int* __restrict__ done,
    const float* __restrict__ room_params,
    const float4* __restrict__ wall,
    float4* __restrict__ dyn)
{
    __shared__ unsigned int   cnt[SWPB][NBUCKETS];   // count -> (wave,bucket) base
    __shared__ unsigned int   pstart[NBUCKETS];      // block-local exclusive prefix
    __shared__ unsigned int   wsum[4];
    __shared__ unsigned short staged[STG_MAX];       // 20 KB
    __shared__ unsigned int   codeLDS[2 * F4PT][512]; // 40 KB, transposed
    __shared__ unsigned int   tailcode;

    int tid  = threadIdx.x;
    int wv   = tid >> 6;
    int lane = tid & 63;

    if (blockIdx.x == 0 && tid == 0) { *maxp = 0u; *done = 0u; }

    #pragma unroll
    for (int i = 0; i < (SWPB * NBUCKETS) / 512; ++i)
        ((unsigned int*)cnt)[tid + 512 * i] = 0u;
    __syncthreads();

    int chunk = (n4 + NBLK - 1) / NBLK;
    int start = blockIdx.x * chunk;
    int end   = min(start + chunk, n4);

    // Phase A: load agents, compute codes, count+rank via one LDS atomic,
    // park packed (bucket:8 | rank:11 | bin:12) in transposed LDS.
    #pragma unroll
    for (int k = 0; k < F4PT; ++k) {
        int i4 = start + (k << 9) + tid;
        if (i4 < end) {
            float4 p = pos[i4];
            int ix0 = min(max((int)(p.x * 1024.0f), 0), 1023);
            int iy0 = min(max((int)(p.y * 1024.0f), 0), 1023);
            int ix1 = min(max((int)(p.z * 1024.0f), 0), 1023);
            int iy1 = min(max((int)(p.w * 1024.0f), 0), 1023);
            unsigned int b0 = (unsigned int)(ix0 >> 2);
            unsigned int b1 = (unsigned int)(ix1 >> 2);
            unsigned int bin0 = (unsigned int)(((ix0 & 3) << 10) | iy0);
            unsigned int bin1 = (unsigned int)(((ix1 & 3) << 10) | iy1);
            unsigned int r0 = atomicAdd(&cnt[wv][b0], 1u);   // <= 1279
            unsigned int r1 = atomicAdd(&cnt[wv][b1], 1u);
            codeLDS[2 * k][tid]     = (b0 << 23) | (r0 << 12) | bin0;
            codeLDS[2 * k + 1][tid] = (b1 << 23) | (r1 << 12) | bin1;
        } else {
            codeLDS[2 * k][tid]     = 0xFFFFFFFFu;
            codeLDS[2 * k + 1][tid] = 0xFFFFFFFFu;
        }
    }

    // odd-count tail agent: counted and parked by block 0 / tid 0 so it
    // flows through the same prefix + staged + copy-out machinery.
    if (blockIdx.x == 0 && tid == 0 && (nagents & 1)) {
        const float* t = (const float*)pos;
        float px = t[2 * (nagents - 1)];
        float py = t[2 * (nagents - 1) + 1];
        int ix = min(max((int)(px * 1024.0f), 0), 1023);
        int iy = min(max((int)(py * 1024.0f), 0), 1023);
        unsigned int b = (unsigned int)(ix >> 2);
        unsigned int r = atomicAdd(&cnt[0][b], 1u);
        tailcode = (b << 23) | (r << 12)
                 | (unsigned int)(((ix & 3) << 10) | iy);
    }

    // Fused dyn-plane computation, mid-kernel: its 32 MB NT-store drain
    // overlaps Phases B-D. 512 blocks * 512 thr == RES*RES/4 exactly.
    dyn_cell(room_params, wall, dyn, blockIdx.x * 512 + tid);

    __syncthreads();

    // Phase B: in-place count->base, block prefix. NO global reservation.
    if (tid < NBUCKETS) {
        unsigned int run = 0;
        #pragma unroll
        for (int w = 0; w < SWPB; ++w) {
            unsigned int c = cnt[w][tid];
            cnt[w][tid] = run;                       // wave-exclusive base
            run += c;
        }
        unsigned int t = run;                        // inclusive scan within wave
        #pragma unroll
        for (int off = 1; off < 64; off <<= 1) {
            unsigned int v = (unsigned int)__shfl_up((int)t, off, 64);
            if (lane >= off) t += v;
        }
        if (lane == 63) wsum[wv] = t;
        pstart[tid] = t - run;                       // wave-local exclusive
    }
    __syncthreads();
    if (tid < NBUCKETS) {
        unsigned int off = 0;
        #pragma unroll
        for (int w = 0; w < 3; ++w) if (w < wv) off += wsum[w];
        unsigned int ps = pstart[tid] + off;         // block-local exclusive prefix
        pstart[tid] = ps;
        #pragma unroll
        for (int w = 0; w < SWPB; ++w) cnt[w][tid] += ps;
        meta[blockIdx.x * NBUCKETS + tid] = (unsigned short)ps;  // coalesced
    }
    __syncthreads();

    // Phase C: scatter codes into LDS staging ordered by bucket.
    #pragma unroll
    for (int k = 0; k < 2 * F4PT; ++k) {
        unsigned int u = codeLDS[k][tid];
        if (u != 0xFFFFFFFFu) {
            unsigned int b   = u >> 23;
            unsigned int r   = (u >> 12) & 0x7FFu;
            staged[cnt[wv][b] + r] = (unsigned short)(u & 0xFFFu);
        }
    }
    if (blockIdx.x == 0 && tid == 0 && (nagents & 1)) {
        unsigned int u = tailcode;
        staged[cnt[0][u >> 23] + ((u >> 12) & 0x7FFu)]
            = (unsigned short)(u & 0xFFFu);
    }
    __syncthreads();

    // Phase D: contiguous vectorized copy-out of the whole staged array.
    unsigned int tot = 2u * (unsigned int)(end - start)
                     + ((blockIdx.x == 0 && (nagents & 1)) ? 1u : 0u);
    unsigned int nw = (tot + 1u) >> 1;               // u32 words
    unsigned int* dst = (unsigned int*)(buf + (size_t)blockIdx.x * STG_MAX);
    const unsigned int* src = (const unsigned int*)staged;
    for (unsigned int i = tid; i < nw; i += 512) dst[i] = src[i];
}

// ---------------------------------------------------------------------------
// Pass 2 (fused hist + norm): one block per bucket.
//   * gather via meta: thread pair (2t,2t+1) splits scatter-block t's
//     segment for this bucket (~19 entries each) -> LDS histogram;
//   * block max -> atomicMax(maxp), release-increment done;
//   * tid 0 acquire-spins for done==NBUCKETS (256 blocks x 1024 thr on
//     256 CUs: 1 block/CU, trivially co-resident -> no deadlock; the
//     identical construct passed rocprof twice in round 4), then
//     flow = h*inv written straight from registers.
// ---------------------------------------------------------------------------
__global__ __launch_bounds__(1024) void hist_norm_kernel(
    const unsigned short* __restrict__ buf,
    const unsigned short* __restrict__ meta,
    int n4, int nagents,
    float* __restrict__ flow,
    unsigned int* __restrict__ maxp,
    unsigned int* __restrict__ done)
{
    __shared__ __align__(16) unsigned int h[BINS_PER_BUCKET];   // 16 KB
    __shared__ unsigned int sm[16];
    __shared__ float sinv;
    int b = blockIdx.x, tid = threadIdx.x;
    #pragma unroll
    for (int i = 0; i < BINS_PER_BUCKET / 1024; ++i) h[tid + 1024 * i] = 0u;
    __syncthreads();

    // segment of scatter-block B for bucket b, split between 2 threads
    int B    = tid >> 1;
    int half = tid & 1;
    int chunk = (n4 + NBLK - 1) / NBLK;
    int start = B * chunk;
    int end   = min(start + chunk, n4);
    unsigned int tot = 2u * (unsigned int)(end - start)
                     + ((B == 0 && (nagents & 1)) ? 1u : 0u);
    unsigned int s = meta[B * NBUCKETS + b];
    unsigned int e = (b < NBUCKETS - 1) ? (unsigned int)meta[B * NBUCKETS + b + 1]
                                        : tot;
    unsigned int c  = e - s;
    unsigned int c0 = (c + 1u) >> 1;
    unsigned int lo = s + (half ? c0 : 0u);
    unsigned int hi = half ? e : (s + c0);
    const unsigned short* seg = buf + (size_t)B * STG_MAX;
    for (unsigned int i = lo; i < hi; ++i)
        atomicAdd(&h[seg[i]], 1u);
    __syncthreads();

    u32x4 v = ((const u32x4*)h)[tid];
    unsigned int m = max(max(v.x, v.y), max(v.z, v.w));
    #pragma unroll
    for (int off = 32; off > 0; off >>= 1)
        m = max(m, (unsigned int)__shfl_down((int)m, off, 64));
    if ((tid & 63) == 0) sm[tid >> 6] = m;
    __syncthreads();
    if (tid == 0) {
        #pragma unroll
        for (int w = 1; w < 16; ++w) m = max(m, sm[w]);
        atomicMax(maxp, m);
        __hip_atomic_fetch_add(done, 1u, __ATOMIC_RELEASE,
                               __HIP_MEMORY_SCOPE_AGENT);
        while (__hip_atomic_load(done, __ATOMIC_ACQUIRE,
                                 __HIP_MEMORY_SCOPE_AGENT) < NBUCKETS)
            __builtin_amdgcn_s_sleep(8);
        unsigned int mx = __hip_atomic_load(maxp, __ATOMIC_RELAXED,
                                            __HIP_MEMORY_SCOPE_AGENT);
        sinv = 1.0f / ((float)mx + 1e-6f);
    }
    __syncthreads();
    float inv = sinv;
    f32x4 o;
    o.x = (float)v.x * inv;
    o.y = (float)v.y * inv;
    o.z = (float)v.z * inv;
    o.w = (float)v.w * inv;
    __builtin_nontemporal_store(
        o, reinterpret_cast<f32x4*>(&((float4*)flow)[b * 1024 + tid]));
}

// ---------------------------------------------------------------------------
// Fallback path (ws too small): direct global atomics + max + full final.
// ---------------------------------------------------------------------------
__global__ __launch_bounds__(256) void hist_atomic_kernel(
    const float4* __restrict__ pos, int n4, int nagents,
    unsigned int* __restrict__ counts)
{
    int idx = blockIdx.x * blockDim.x + threadIdx.x;
    int stride = gridDim.x * blockDim.x;
    for (int i = idx; i < n4; i += stride) {
        float4 p = pos[i];
        int ix0 = min(max((int)(p.x * 1024.0f), 0), 1023);
        int iy0 = min(max((int)(p.y * 1024.0f), 0), 1023);
        int ix1 = min(max((int)(p.z * 1024.0f), 0), 1023);
        int iy1 = min(max((int)(p.w * 1024.0f), 0), 1023);
        atomicAdd(&counts[(ix0 << 10) + iy0], 1u);
        atomicAdd(&counts[(ix1 << 10) + iy1], 1u);
    }
    if (idx == 0 && (nagents & 1)) {
        const float* t = (const float*)pos;
        int ix = min(max((int)(t[2 * (nagents - 1)] * 1024.0f), 0), 1023);
        int iy = min(max((int)(t[2 * (nagents - 1) + 1] * 1024.0f), 0), 1023);
        atomicAdd(&counts[(ix << 10) + iy], 1u);
    }
}

__global__ __launch_bounds__(256) void max_kernel(
    const uint4* __restrict__ counts, unsigned int* __restrict__ out_max)
{
    int idx = blockIdx.x * blockDim.x + threadIdx.x;
    int stride = gridDim.x * blockDim.x;
    unsigned int m = 0;
    const int n4 = (RES * RES) / 4;
    for (int i = idx; i < n4; i += stride) {
        uint4 c = counts[i];
        m = max(m, max(max(c.x, c.y), max(c.z, c.w)));
    }
    #pragma unroll
    for (int off = 32; off > 0; off >>= 1)
        m = max(m, (unsigned int)__shfl_down((int)m, off, 64));
    __shared__ unsigned int sm[4];
    if ((threadIdx.x & 63) == 0) sm[threadIdx.x >> 6] = m;
    __syncthreads();
    if (threadIdx.x == 0) {
        m = max(max(sm[0], sm[1]), max(sm[2], sm[3]));
        atomicMax(out_max, m);
    }
}

__global__ __launch_bounds__(256) void final_full_kernel(
    const float* __restrict__ room_params,
    const float4* __restrict__ wall,
    float4* __restrict__ dyn,
    float* __restrict__ flow,
    const unsigned int* __restrict__ maxp)
{
    int idx = blockIdx.x * blockDim.x + threadIdx.x;   // 0 .. 262143
    uint4 c = ((const uint4*)flow)[idx];
    float inv = 1.0f / ((float)(*maxp) + 1e-6f);
    ((float4*)flow)[idx] = make_float4((float)c.x * inv, (float)c.y * inv,
                                       (float)c.z * inv, (float)c.w * inv);
    dyn_cell(room_params, wall, dyn, idx);
}

extern "C" void kernel_launch(void* const* d_in, const int* in_sizes, int n_in,
                              void* d_out, int out_size, void* d_ws, size_t ws_size,
                              hipStream_t stream) {
    const float* agents      = (const float*)d_in[0];  // (N,2)
    const float* room_params = (const float*)d_in[1];  // (8,4)
    const float* wall        = (const float*)d_in[2];  // (1024,1024)

    float* dyn  = (float*)d_out;
    float* flow = (float*)d_out + (size_t)NROOMS * RES * RES;
    unsigned int* counts = (unsigned int*)flow;

    int nagents = in_sizes[0] / 2;
    int n4 = nagents / 2;

    // ws layout: [0,4) maxp, [4,8) done,
    //            [1024, 1024+128KB) meta, [512KB, 512KB+10MB) buf
    size_t meta_off = 1024;
    size_t buf_off  = 512 * 1024;
    size_t need = buf_off + (size_t)NBLK * STG_MAX * sizeof(unsigned short);

    // main path requires the per-block agent range to fit F4PT float4/thread
    bool fits = ((n4 + NBLK - 1) / NBLK) <= (F4PT * 512);

    if (ws_size >= need && fits) {
        unsigned int*   maxp = (unsigned int*)d_ws;
        unsigned int*   done = (unsigned int*)((char*)d_ws + 4);
        unsigned short* meta = (unsigned short*)((char*)d_ws + meta_off);
        unsigned short* buf  = (unsigned short*)((char*)d_ws + buf_off);

        scatter_kernel<<<NBLK, 512, 0, stream>>>(
            (const float4*)agents, n4, nagents, buf, meta, maxp, done,
            room_params, (const float4*)wall, (float4*)dyn);
        hist_norm_kernel<<<NBUCKETS, 1024, 0, stream>>>(
            buf, meta, n4, nagents, flow, maxp, done);
    } else {
        unsigned int* maxp = (unsigned int*)d_ws;
        (void)hipMemsetAsync(flow, 0, (size_t)RES * RES * sizeof(float), stream);
        (void)hipMemsetAsync(maxp, 0, sizeof(unsigned int), stream);
        hist_atomic_kernel<<<1280, 256, 0, stream>>>((const float4*)agents, n4, nagents, counts);
        max_kernel<<<256, 256, 0, stream>>>((const uint4*)counts, maxp);
        final_full_kernel<<<(RES * RES / 4) / 256, 256, 0, stream>>>(
            room_params, (const float4*)wall, (float4*)dyn, flow, maxp);
    }
}

// Round 7
// 140.362 us; speedup vs baseline: 1.1957x; 1.1957x over previous
//
#include <hip/hip_runtime.h>

#define RES 1024
#define NROOMS 8
#define NBUCKETS 256                 // 4 grid rows per bucket
#define BINS_PER_BUCKET (4 * RES)    // 4096 bins
#define SWPB 8                       // waves per scatter block (512 threads)
#define NBLK 512                     // exactly 2 blocks/CU
#define F4PT 10                      // max float4 per thread (ceil(2.5M/512/512))
#define STG_MAX (512 * F4PT * 2)     // 10240 entries staged per block (20 KB)

typedef unsigned int u32x4 __attribute__((ext_vector_type(4)));
typedef float        f32x4 __attribute__((ext_vector_type(4)));

// ---------------------------------------------------------------------------
// Device helper: compute one grid cell (4 columns) of all 8 dyn planes.
// NT stores: dyn (32 MB) is never re-read; keep it out of L2.
// ---------------------------------------------------------------------------
__device__ __forceinline__ void dyn_cell(
    const float* __restrict__ room_params,
    const float4* __restrict__ wall,
    float4* __restrict__ dyn, int idx)
{
    int i  = idx >> 8;
    int j0 = (idx & 255) << 2;
    const float inv1023 = 1.0f / 1023.0f;
    float x  = (float)i * inv1023;
    float y0 = (float)(j0 + 0) * inv1023;
    float y1 = (float)(j0 + 1) * inv1023;
    float y2 = (float)(j0 + 2) * inv1023;
    float y3 = (float)(j0 + 3) * inv1023;

    float4 w = wall[idx];
    float omx = 1.0f - w.x;
    float omy = 1.0f - w.y;
    float omz = 1.0f - w.z;
    float omw = 1.0f - w.w;

    const int plane4 = (RES * RES) / 4;
    #pragma unroll
    for (int r = 0; r < NROOMS; ++r) {
        float cx = room_params[4 * r + 0];
        float cy = room_params[4 * r + 1];
        float sx = room_params[4 * r + 2];
        float sy = room_params[4 * r + 3];
        float isx = 1.0f / (2.0f * sx * sx);
        float isy = 1.0f / (2.0f * sy * sy);
        float dx = x - cx;
        float ax = dx * dx * isx;
        float d0 = y0 - cy, d1 = y1 - cy, d2 = y2 - cy, d3 = y3 - cy;
        f32x4 d;
        d.x = __expf(-(ax + d0 * d0 * isy)) * omx;
        d.y = __expf(-(ax + d1 * d1 * isy)) * omy;
        d.z = __expf(-(ax + d2 * d2 * isy)) * omz;
        d.w = __expf(-(ax + d3 * d3 * isy)) * omw;
        __builtin_nontemporal_store(
            d, reinterpret_cast<f32x4*>(&dyn[(size_t)r * plane4 + idx]));
    }
}

// ---------------------------------------------------------------------------
// Pass 1: unchanged from round 5 (passed, correct, scatter below top-5):
// LDS code parking, dyn fused mid-kernel, deterministic per-block buf
// layout + meta prefix table, contiguous vectorized copy-out, block 0
// zeroes maxp/done (no memset dispatch).
// ---------------------------------------------------------------------------
__global__ __launch_bounds__(512, 4) void scatter_kernel(
    const float4* __restrict__ pos, int n4, int nagents,
    unsigned short* __restrict__ buf, unsigned short* __restrict__ meta,
    unsigned int* __restrict__ maxp, unsigned int* __restrict__ done,
    const float* __restrict__ room_params,
    const float4* __restrict__ wall,
    float4* __restrict__ dyn)
{
    __shared__ unsigned int   cnt[SWPB][NBUCKETS];   // count -> (wave,bucket) base
    __shared__ unsigned int   pstart[NBUCKETS];      // block-local exclusive prefix
    __shared__ unsigned int   wsum[4];
    __shared__ unsigned short staged[STG_MAX];       // 20 KB
    __shared__ unsigned int   codeLDS[2 * F4PT][512]; // 40 KB, transposed
    __shared__ unsigned int   tailcode;

    int tid  = threadIdx.x;
    int wv   = tid >> 6;
    int lane = tid & 63;

    if (blockIdx.x == 0 && tid == 0) { *maxp = 0u; *done = 0u; }

    #pragma unroll
    for (int i = 0; i < (SWPB * NBUCKETS) / 512; ++i)
        ((unsigned int*)cnt)[tid + 512 * i] = 0u;
    __syncthreads();

    int chunk = (n4 + NBLK - 1) / NBLK;
    int start = blockIdx.x * chunk;
    int end   = min(start + chunk, n4);

    // Phase A: load agents, compute codes, count+rank via one LDS atomic,
    // park packed (bucket:8 | rank:11 | bin:12) in transposed LDS.
    #pragma unroll
    for (int k = 0; k < F4PT; ++k) {
        int i4 = start + (k << 9) + tid;
        if (i4 < end) {
            float4 p = pos[i4];
            int ix0 = min(max((int)(p.x * 1024.0f), 0), 1023);
            int iy0 = min(max((int)(p.y * 1024.0f), 0), 1023);
            int ix1 = min(max((int)(p.z * 1024.0f), 0), 1023);
            int iy1 = min(max((int)(p.w * 1024.0f), 0), 1023);
            unsigned int b0 = (unsigned int)(ix0 >> 2);
            unsigned int b1 = (unsigned int)(ix1 >> 2);
            unsigned int bin0 = (unsigned int)(((ix0 & 3) << 10) | iy0);
            unsigned int bin1 = (unsigned int)(((ix1 & 3) << 10) | iy1);
            unsigned int r0 = atomicAdd(&cnt[wv][b0], 1u);   // <= 1279
            unsigned int r1 = atomicAdd(&cnt[wv][b1], 1u);
            codeLDS[2 * k][tid]     = (b0 << 23) | (r0 << 12) | bin0;
            codeLDS[2 * k + 1][tid] = (b1 << 23) | (r1 << 12) | bin1;
        } else {
            codeLDS[2 * k][tid]     = 0xFFFFFFFFu;
            codeLDS[2 * k + 1][tid] = 0xFFFFFFFFu;
        }
    }

    // odd-count tail agent: counted and parked by block 0 / tid 0 so it
    // flows through the same prefix + staged + copy-out machinery.
    if (blockIdx.x == 0 && tid == 0 && (nagents & 1)) {
        const float* t = (const float*)pos;
        float px = t[2 * (nagents - 1)];
        float py = t[2 * (nagents - 1) + 1];
        int ix = min(max((int)(px * 1024.0f), 0), 1023);
        int iy = min(max((int)(py * 1024.0f), 0), 1023);
        unsigned int b = (unsigned int)(ix >> 2);
        unsigned int r = atomicAdd(&cnt[0][b], 1u);
        tailcode = (b << 23) | (r << 12)
                 | (unsigned int)(((ix & 3) << 10) | iy);
    }

    // Fused dyn-plane computation, mid-kernel: its 32 MB NT-store drain
    // overlaps Phases B-D. 512 blocks * 512 thr == RES*RES/4 exactly.
    dyn_cell(room_params, wall, dyn, blockIdx.x * 512 + tid);

    __syncthreads();

    // Phase B: in-place count->base, block prefix. NO global reservation.
    if (tid < NBUCKETS) {
        unsigned int run = 0;
        #pragma unroll
        for (int w = 0; w < SWPB; ++w) {
            unsigned int c = cnt[w][tid];
            cnt[w][tid] = run;                       // wave-exclusive base
            run += c;
        }
        unsigned int t = run;                        // inclusive scan within wave
        #pragma unroll
        for (int off = 1; off < 64; off <<= 1) {
            unsigned int v = (unsigned int)__shfl_up((int)t, off, 64);
            if (lane >= off) t += v;
        }
        if (lane == 63) wsum[wv] = t;
        pstart[tid] = t - run;                       // wave-local exclusive
    }
    __syncthreads();
    if (tid < NBUCKETS) {
        unsigned int off = 0;
        #pragma unroll
        for (int w = 0; w < 3; ++w) if (w < wv) off += wsum[w];
        unsigned int ps = pstart[tid] + off;         // block-local exclusive prefix
        pstart[tid] = ps;
        #pragma unroll
        for (int w = 0; w < SWPB; ++w) cnt[w][tid] += ps;
        meta[blockIdx.x * NBUCKETS + tid] = (unsigned short)ps;  // coalesced
    }
    __syncthreads();

    // Phase C: scatter codes into LDS staging ordered by bucket.
    #pragma unroll
    for (int k = 0; k < 2 * F4PT; ++k) {
        unsigned int u = codeLDS[k][tid];
        if (u != 0xFFFFFFFFu) {
            unsigned int b   = u >> 23;
            unsigned int r   = (u >> 12) & 0x7FFu;
            staged[cnt[wv][b] + r] = (unsigned short)(u & 0xFFFu);
        }
    }
    if (blockIdx.x == 0 && tid == 0 && (nagents & 1)) {
        unsigned int u = tailcode;
        staged[cnt[0][u >> 23] + ((u >> 12) & 0x7FFu)]
            = (unsigned short)(u & 0xFFFu);
    }
    __syncthreads();

    // Phase D: contiguous vectorized copy-out of the whole staged array.
    unsigned int tot = 2u * (unsigned int)(end - start)
                     + ((blockIdx.x == 0 && (nagents & 1)) ? 1u : 0u);
    unsigned int nw = (tot + 1u) >> 1;               // u32 words
    unsigned int* dst = (unsigned int*)(buf + (size_t)blockIdx.x * STG_MAX);
    const unsigned int* src = (const unsigned int*)staged;
    for (unsigned int i = tid; i < nw; i += 512) dst[i] = src[i];
}

// ---------------------------------------------------------------------------
// Pass 2 (fused hist + norm): one block per bucket.
//
// ROUND-7 FIX: round 6's thread-pair gather was latency-bound (80 µs,
// 250 GB/s, VALUBusy 1.4% — each wave-load touched 32 cache lines with
// ~1 outstanding load). Now each WAVE owns one scatter-block strip:
// the strip [meta[B][b], meta[B][b+1]) is contiguous (~40 u16), so
// lane-strided reads are 1-2 fully-coalesced accesses; 16 waves sweep
// the 512 segments in 32 rounds with high MLP.
//   * block max -> atomicMax(maxp), release-increment done;
//   * tid 0 acquire-spins for done==NBUCKETS (256 blocks x 1024 thr on
//     256 CUs: 1 block/CU, co-resident -> no deadlock; construct passed
//     rocprof in rounds 4 and 6), then flow = h*inv from registers.
// ---------------------------------------------------------------------------
__global__ __launch_bounds__(1024) void hist_norm_kernel(
    const unsigned short* __restrict__ buf,
    const unsigned short* __restrict__ meta,
    int n4, int nagents,
    float* __restrict__ flow,
    unsigned int* __restrict__ maxp,
    unsigned int* __restrict__ done)
{
    __shared__ __align__(16) unsigned int h[BINS_PER_BUCKET];   // 16 KB
    __shared__ unsigned int sm[16];
    __shared__ float sinv;
    int b = blockIdx.x, tid = threadIdx.x;
    int wv = tid >> 6, lane = tid & 63;
    #pragma unroll
    for (int i = 0; i < BINS_PER_BUCKET / 1024; ++i) h[tid + 1024 * i] = 0u;
    __syncthreads();

    int chunk = (n4 + NBLK - 1) / NBLK;
    for (int B = wv; B < NBLK; B += 16) {
        int start = B * chunk;
        int end   = min(start + chunk, n4);
        unsigned int tot = 2u * (unsigned int)(end - start)
                         + ((B == 0 && (nagents & 1)) ? 1u : 0u);
        unsigned int s = meta[B * NBUCKETS + b];
        unsigned int e = (b < NBUCKETS - 1)
                       ? (unsigned int)meta[B * NBUCKETS + b + 1] : tot;
        const unsigned short* seg = buf + (size_t)B * STG_MAX;
        for (unsigned int i = s + lane; i < e; i += 64)
            atomicAdd(&h[seg[i]], 1u);
    }
    __syncthreads();

    u32x4 v = ((const u32x4*)h)[tid];
    unsigned int m = max(max(v.x, v.y), max(v.z, v.w));
    #pragma unroll
    for (int off = 32; off > 0; off >>= 1)
        m = max(m, (unsigned int)__shfl_down((int)m, off, 64));
    if ((tid & 63) == 0) sm[tid >> 6] = m;
    __syncthreads();
    if (tid == 0) {
        #pragma unroll
        for (int w = 1; w < 16; ++w) m = max(m, sm[w]);
        atomicMax(maxp, m);
        __hip_atomic_fetch_add(done, 1u, __ATOMIC_RELEASE,
                               __HIP_MEMORY_SCOPE_AGENT);
        while (__hip_atomic_load(done, __ATOMIC_ACQUIRE,
                                 __HIP_MEMORY_SCOPE_AGENT) < NBUCKETS)
            __builtin_amdgcn_s_sleep(8);
        unsigned int mx = __hip_atomic_load(maxp, __ATOMIC_RELAXED,
                                            __HIP_MEMORY_SCOPE_AGENT);
        sinv = 1.0f / ((float)mx + 1e-6f);
    }
    __syncthreads();
    float inv = sinv;
    f32x4 o;
    o.x = (float)v.x * inv;
    o.y = (float)v.y * inv;
    o.z = (float)v.z * inv;
    o.w = (float)v.w * inv;
    __builtin_nontemporal_store(
        o, reinterpret_cast<f32x4*>(&((float4*)flow)[b * 1024 + tid]));
}

// ---------------------------------------------------------------------------
// Fallback path (ws too small): direct global atomics + max + full final.
// ---------------------------------------------------------------------------
__global__ __launch_bounds__(256) void hist_atomic_kernel(
    const float4* __restrict__ pos, int n4, int nagents,
    unsigned int* __restrict__ counts)
{
    int idx = blockIdx.x * blockDim.x + threadIdx.x;
    int stride = gridDim.x * blockDim.x;
    for (int i = idx; i < n4; i += stride) {
        float4 p = pos[i];
        int ix0 = min(max((int)(p.x * 1024.0f), 0), 1023);
        int iy0 = min(max((int)(p.y * 1024.0f), 0), 1023);
        int ix1 = min(max((int)(p.z * 1024.0f), 0), 1023);
        int iy1 = min(max((int)(p.w * 1024.0f), 0), 1023);
        atomicAdd(&counts[(ix0 << 10) + iy0], 1u);
        atomicAdd(&counts[(ix1 << 10) + iy1], 1u);
    }
    if (idx == 0 && (nagents & 1)) {
        const float* t = (const float*)pos;
        int ix = min(max((int)(t[2 * (nagents - 1)] * 1024.0f), 0), 1023);
        int iy = min(max((int)(t[2 * (nagents - 1) + 1] * 1024.0f), 0), 1023);
        atomicAdd(&counts[(ix << 10) + iy], 1u);
    }
}

__global__ __launch_bounds__(256) void max_kernel(
    const uint4* __restrict__ counts, unsigned int* __restrict__ out_max)
{
    int idx = blockIdx.x * blockDim.x + threadIdx.x;
    int stride = gridDim.x * blockDim.x;
    unsigned int m = 0;
    const int n4 = (RES * RES) / 4;
    for (int i = idx; i < n4; i += stride) {
        uint4 c = counts[i];
        m = max(m, max(max(c.x, c.y), max(c.z, c.w)));
    }
    #pragma unroll
    for (int off = 32; off > 0; off >>= 1)
        m = max(m, (unsigned int)__shfl_down((int)m, off, 64));
    __shared__ unsigned int sm[4];
    if ((threadIdx.x & 63) == 0) sm[threadIdx.x >> 6] = m;
    __syncthreads();
    if (threadIdx.x == 0) {
        m = max(max(sm[0], sm[1]), max(sm[2], sm[3]));
        atomicMax(out_max, m);
    }
}

__global__ __launch_bounds__(256) void final_full_kernel(
    const float* __restrict__ room_params,
    const float4* __restrict__ wall,
    float4* __restrict__ dyn,
    float* __restrict__ flow,
    const unsigned int* __restrict__ maxp)
{
    int idx = blockIdx.x * blockDim.x + threadIdx.x;   // 0 .. 262143
    uint4 c = ((const uint4*)flow)[idx];
    float inv = 1.0f / ((float)(*maxp) + 1e-6f);
    ((float4*)flow)[idx] = make_float4((float)c.x * inv, (float)c.y * inv,
                                       (float)c.z * inv, (float)c.w * inv);
    dyn_cell(room_params, wall, dyn, idx);
}

extern "C" void kernel_launch(void* const* d_in, const int* in_sizes, int n_in,
                              void* d_out, int out_size, void* d_ws, size_t ws_size,
                              hipStream_t stream) {
    const float* agents      = (const float*)d_in[0];  // (N,2)
    const float* room_params = (const float*)d_in[1];  // (8,4)
    const float* wall        = (const float*)d_in[2];  // (1024,1024)

    float* dyn  = (float*)d_out;
    float* flow = (float*)d_out + (size_t)NROOMS * RES * RES;
    unsigned int* counts = (unsigned int*)flow;

    int nagents = in_sizes[0] / 2;
    int n4 = nagents / 2;

    // ws layout: [0,4) maxp, [4,8) done,
    //            [1024, 1024+256KB) meta, [512KB, 512KB+10MB) buf
    size_t meta_off = 1024;
    size_t buf_off  = 512 * 1024;
    size_t need = buf_off + (size_t)NBLK * STG_MAX * sizeof(unsigned short);

    // main path requires the per-block agent range to fit F4PT float4/thread
    bool fits = ((n4 + NBLK - 1) / NBLK) <= (F4PT * 512);

    if (ws_size >= need && fits) {
        unsigned int*   maxp = (unsigned int*)d_ws;
        unsigned int*   done = (unsigned int*)((char*)d_ws + 4);
        unsigned short* meta = (unsigned short*)((char*)d_ws + meta_off);
        unsigned short* buf  = (unsigned short*)((char*)d_ws + buf_off);

        scatter_kernel<<<NBLK, 512, 0, stream>>>(
            (const float4*)agents, n4, nagents, buf, meta, maxp, done,
            room_params, (const float4*)wall, (float4*)dyn);
        hist_norm_kernel<<<NBUCKETS, 1024, 0, stream>>>(
            buf, meta, n4, nagents, flow, maxp, done);
    } else {
        unsigned int* maxp = (unsigned int*)d_ws;
        (void)hipMemsetAsync(flow, 0, (size_t)RES * RES * sizeof(float), stream);
        (void)hipMemsetAsync(maxp, 0, sizeof(unsigned int), stream);
        hist_atomic_kernel<<<1280, 256, 0, stream>>>((const float4*)agents, n4, nagents, counts);
        max_kernel<<<256, 256, 0, stream>>>((const uint4*)counts, maxp);
        final_full_kernel<<<(RES * RES / 4) / 256, 256, 0, stream>>>(
            room_params, (const float4*)wall, (float4*)dyn, flow, maxp);
    }
}

// Round 8
// 122.248 us; speedup vs baseline: 1.3729x; 1.1482x over previous
//
#include <hip/hip_runtime.h>

#define RES 1024
#define NROOMS 8
#define NBUCKETS 256                 // 4 grid rows per bucket
#define BINS_PER_BUCKET (4 * RES)    // 4096 bins
#define CAP 32768                    // entries per bucket (mean ~19531, sigma ~140)
#define SWPB 8                       // waves per scatter block (512 threads)
#define NBLK 768                     // exactly 3 blocks/CU
#define F4PT 7                       // max float4 per thread (ceil(2.5M/768/512)=7)
#define STG_MAX (512 * F4PT * 2)     // 7168 entries staged per block (14 KB)

typedef unsigned int u32x4 __attribute__((ext_vector_type(4)));
typedef float        f32x4 __attribute__((ext_vector_type(4)));

// ---------------------------------------------------------------------------
// Device helper: compute one grid cell (4 columns) of all 8 dyn planes.
// NT stores: dyn (32 MB) is never re-read; keep it out of L2 (preserves
// residency for buf, which hist_build re-reads).
// ---------------------------------------------------------------------------
__device__ __forceinline__ void dyn_cell(
    const float* __restrict__ room_params,
    const float4* __restrict__ wall,
    float4* __restrict__ dyn, int idx)
{
    int i  = idx >> 8;
    int j0 = (idx & 255) << 2;
    const float inv1023 = 1.0f / 1023.0f;
    float x  = (float)i * inv1023;
    float y0 = (float)(j0 + 0) * inv1023;
    float y1 = (float)(j0 + 1) * inv1023;
    float y2 = (float)(j0 + 2) * inv1023;
    float y3 = (float)(j0 + 3) * inv1023;

    float4 w = wall[idx];
    float omx = 1.0f - w.x;
    float omy = 1.0f - w.y;
    float omz = 1.0f - w.z;
    float omw = 1.0f - w.w;

    const int plane4 = (RES * RES) / 4;
    #pragma unroll
    for (int r = 0; r < NROOMS; ++r) {
        float cx = room_params[4 * r + 0];
        float cy = room_params[4 * r + 1];
        float sx = room_params[4 * r + 2];
        float sy = room_params[4 * r + 3];
        float isx = 1.0f / (2.0f * sx * sx);
        float isy = 1.0f / (2.0f * sy * sy);
        float dx = x - cx;
        float ax = dx * dx * isx;
        float d0 = y0 - cy, d1 = y1 - cy, d2 = y2 - cy, d3 = y3 - cy;
        f32x4 d;
        d.x = __expf(-(ax + d0 * d0 * isy)) * omx;
        d.y = __expf(-(ax + d1 * d1 * isy)) * omy;
        d.z = __expf(-(ax + d2 * d2 * isy)) * omz;
        d.w = __expf(-(ax + d3 * d3 * isy)) * omw;
        __builtin_nontemporal_store(
            d, reinterpret_cast<f32x4*>(&dyn[(size_t)r * plane4 + idx]));
    }
}

// ---------------------------------------------------------------------------
// Pass 1: ROUND-3 structure (best measured: 118.4 total) with one change —
// LDS trimmed to 52.2 KB so THREE blocks fit per CU (24 waves, was 16):
//   * NBLK=768 (exactly 3/CU), F4PT=7;
//   * code pairs parked as ONE uint2 per k (ds_write_b64 / ds_read_b64,
//     halves the LDS instruction count of phases A/C);
//   * pstart/gbase stored as u16 (values < 32768); ptotal dropped
//     (recomputed in Phase D from pstart diffs).
// Cursor-based global reservation + bucket-major buf retained: R7 proved
// the cursor atomics are cheap, and bucket-major buf is what makes
// hist_build's read a single contiguous coalesced stream (the fastest
// pass-2 measured). The done-spin fusion (R4/R6/R7) is abandoned: every
// spin variant measured ~20+ us worse than the split hist+norm.
// ---------------------------------------------------------------------------
__global__ __launch_bounds__(512, 6) void scatter_kernel(
    const float4* __restrict__ pos, int n4, int nagents,
    unsigned short* __restrict__ buf, unsigned int* __restrict__ cursor,
    const float* __restrict__ room_params,
    const float4* __restrict__ wall,
    float4* __restrict__ dyn)
{
    __shared__ unsigned int   cnt[SWPB][NBUCKETS];    // 8 KB: count -> base
    __shared__ unsigned short pstart[NBUCKETS];       // 512 B: block prefix
    __shared__ unsigned short gbase[NBUCKETS];        // 512 B: global base
    __shared__ unsigned int   wsum[4];
    __shared__ unsigned short staged[STG_MAX];        // 14 KB
    __shared__ uint2          codeLDS[F4PT][512];     // 28 KB, transposed pairs

    int tid  = threadIdx.x;
    int wv   = tid >> 6;
    int lane = tid & 63;

    #pragma unroll
    for (int i = 0; i < (SWPB * NBUCKETS) / 512; ++i)
        ((unsigned int*)cnt)[tid + 512 * i] = 0u;
    __syncthreads();

    int chunk = (n4 + NBLK - 1) / NBLK;
    int start = blockIdx.x * chunk;
    int end   = min(start + chunk, n4);

    // Phase A: load agents, compute codes, count+rank via one LDS atomic,
    // park packed (bucket:8 | rank:11 | bin:12) PAIRS via ds_write_b64.
    #pragma unroll
    for (int k = 0; k < F4PT; ++k) {
        int i4 = start + (k << 9) + tid;
        if (i4 < end) {
            float4 p = pos[i4];
            int ix0 = min(max((int)(p.x * 1024.0f), 0), 1023);
            int iy0 = min(max((int)(p.y * 1024.0f), 0), 1023);
            int ix1 = min(max((int)(p.z * 1024.0f), 0), 1023);
            int iy1 = min(max((int)(p.w * 1024.0f), 0), 1023);
            unsigned int b0 = (unsigned int)(ix0 >> 2);
            unsigned int b1 = (unsigned int)(ix1 >> 2);
            unsigned int bin0 = (unsigned int)(((ix0 & 3) << 10) | iy0);
            unsigned int bin1 = (unsigned int)(((ix1 & 3) << 10) | iy1);
            unsigned int r0 = atomicAdd(&cnt[wv][b0], 1u);   // <= 895, fits 11b
            unsigned int r1 = atomicAdd(&cnt[wv][b1], 1u);
            codeLDS[k][tid] = make_uint2((b0 << 23) | (r0 << 12) | bin0,
                                         (b1 << 23) | (r1 << 12) | bin1);
        } else {
            codeLDS[k][tid] = make_uint2(0xFFFFFFFFu, 0xFFFFFFFFu);
        }
    }

    // Fused dyn-plane computation, mid-kernel (R3 placement): its 32 MB
    // NT-store drain overlaps Phases B-D. 768 * 512 threads: grid-stride
    // over the 262144 float4 cells (2 cells for the first 128 blocks).
    {
        int cells = (RES * RES) / 4;                  // 262144
        for (int idx = blockIdx.x * 512 + tid; idx < cells; idx += NBLK * 512)
            dyn_cell(room_params, wall, dyn, idx);
    }

    __syncthreads();

    // Phase B: in-place count->base, block prefix, global reservation.
    if (tid < NBUCKETS) {
        unsigned int run = 0;
        #pragma unroll
        for (int w = 0; w < SWPB; ++w) {
            unsigned int c = cnt[w][tid];
            cnt[w][tid] = run;                       // wave-exclusive base
            run += c;
        }
        gbase[tid] = (unsigned short)(run ? atomicAdd(&cursor[tid], run) : 0u);
        unsigned int t = run;                        // inclusive scan within wave
        #pragma unroll
        for (int off = 1; off < 64; off <<= 1) {
            unsigned int v = (unsigned int)__shfl_up((int)t, off, 64);
            if (lane >= off) t += v;
        }
        if (lane == 63) wsum[wv] = t;
        pstart[tid] = (unsigned short)(t - run);     // wave-local exclusive
    }
    __syncthreads();
    if (tid < NBUCKETS) {
        unsigned int off = 0;
        #pragma unroll
        for (int w = 0; w < 3; ++w) if (w < wv) off += wsum[w];
        unsigned int ps = (unsigned int)pstart[tid] + off;   // block prefix
        pstart[tid] = (unsigned short)ps;
        #pragma unroll
        for (int w = 0; w < SWPB; ++w) cnt[w][tid] += ps;
    }
    __syncthreads();

    // Phase C: scatter codes into LDS staging ordered by bucket
    // (ds_read_b64 per k; both codes of a pair share validity).
    #pragma unroll
    for (int k = 0; k < F4PT; ++k) {
        uint2 u = codeLDS[k][tid];
        if (u.x != 0xFFFFFFFFu) {
            staged[cnt[wv][u.x >> 23] + ((u.x >> 12) & 0x7FFu)]
                = (unsigned short)(u.x & 0xFFFu);
            staged[cnt[wv][u.y >> 23] + ((u.y >> 12) & 0x7FFu)]
                = (unsigned short)(u.y & 0xFFFu);
        }
    }
    __syncthreads();

    // Phase D: coalesced copy-out; wave w owns buckets [32w, 32w+32).
    unsigned int tot = 2u * (unsigned int)(end - start);
    #pragma unroll 4
    for (int bb = 0; bb < 32; ++bb) {
        int b = (wv << 5) + bb;
        unsigned int ps = pstart[b];
        unsigned int nx = (b < NBUCKETS - 1) ? (unsigned int)pstart[b + 1] : tot;
        unsigned int n  = nx - ps;
        unsigned int gb = gbase[b];
        for (unsigned int e = lane; e < n; e += 64) {
            unsigned int p = gb + e;
            if (p < CAP) buf[b * CAP + p] = staged[ps + e];
        }
    }

    // odd-count tail agent: direct reservation (R3 path)
    if (blockIdx.x == 0 && tid == 0 && (nagents & 1)) {
        const float* t = (const float*)pos;
        float px = t[2 * (nagents - 1)];
        float py = t[2 * (nagents - 1) + 1];
        int ix = min(max((int)(px * 1024.0f), 0), 1023);
        int iy = min(max((int)(py * 1024.0f), 0), 1023);
        unsigned int b = (unsigned int)(ix >> 2);
        unsigned int p = atomicAdd(&cursor[b], 1u);
        if (p < CAP) buf[b * CAP + p] = (unsigned short)(((ix & 3) << 10) | iy);
    }
}

// ---------------------------------------------------------------------------
// Pass 2: one block per bucket — contiguous paired-code reads (bucket-major
// buf), LDS histogram, uint4 counts store, fused block-max + one atomicMax.
// Exactly the round-3 version (fastest pass-2 measured).
// ---------------------------------------------------------------------------
__global__ __launch_bounds__(1024) void hist_build_kernel(
    const unsigned short* __restrict__ buf,
    const unsigned int* __restrict__ cursor,
    unsigned int* __restrict__ counts,
    unsigned int* __restrict__ out_max)
{
    __shared__ __align__(16) unsigned int h[BINS_PER_BUCKET];   // 16 KB
    int b = blockIdx.x, tid = threadIdx.x;
    #pragma unroll
    for (int i = 0; i < BINS_PER_BUCKET / 1024; ++i) h[tid + 1024 * i] = 0u;
    __syncthreads();

    unsigned int n = min(cursor[b], (unsigned int)CAP);
    const unsigned short* seg = buf + (size_t)b * CAP;
    unsigned int n2 = n & ~1u;
    for (unsigned int i = 2 * tid; i < n2; i += 2048) {
        unsigned int u = *(const unsigned int*)(seg + i);   // seg 4B-aligned, i even
        atomicAdd(&h[u & 0xFFFFu], 1u);
        atomicAdd(&h[u >> 16], 1u);
    }
    if (tid == 0 && (n & 1)) atomicAdd(&h[seg[n - 1]], 1u);
    __syncthreads();

    u32x4 v = ((const u32x4*)h)[tid];
    ((u32x4*)counts)[(size_t)b * (BINS_PER_BUCKET / 4) + tid] = v;
    unsigned int m = max(max(v.x, v.y), max(v.z, v.w));
    #pragma unroll
    for (int off = 32; off > 0; off >>= 1)
        m = max(m, (unsigned int)__shfl_down((int)m, off, 64));
    __shared__ unsigned int sm[16];
    if ((tid & 63) == 0) sm[tid >> 6] = m;
    __syncthreads();
    if (tid == 0) {
        #pragma unroll
        for (int w = 1; w < 16; ++w) m = max(m, sm[w]);
        atomicMax(out_max, m);
    }
}

// ---------------------------------------------------------------------------
// Pass 3 (main path): normalize flow counts in place. Counts are L2-warm.
// ---------------------------------------------------------------------------
__global__ __launch_bounds__(256) void norm_kernel(
    float* __restrict__ flow, const unsigned int* __restrict__ maxp)
{
    int idx = blockIdx.x * blockDim.x + threadIdx.x;   // 0 .. 65535
    uint4 c = ((const uint4*)flow)[idx];
    float inv = 1.0f / ((float)(*maxp) + 1e-6f);
    ((float4*)flow)[idx] = make_float4((float)c.x * inv, (float)c.y * inv,
                                       (float)c.z * inv, (float)c.w * inv);
}

// ---------------------------------------------------------------------------
// Fallback path (ws too small): direct global atomics + max + full final.
// ---------------------------------------------------------------------------
__global__ __launch_bounds__(256) void hist_atomic_kernel(
    const float4* __restrict__ pos, int n4, int nagents,
    unsigned int* __restrict__ counts)
{
    int idx = blockIdx.x * blockDim.x + threadIdx.x;
    int stride = gridDim.x * blockDim.x;
    for (int i = idx; i < n4; i += stride) {
        float4 p = pos[i];
        int ix0 = min(max((int)(p.x * 1024.0f), 0), 1023);
        int iy0 = min(max((int)(p.y * 1024.0f), 0), 1023);
        int ix1 = min(max((int)(p.z * 1024.0f), 0), 1023);
        int iy1 = min(max((int)(p.w * 1024.0f), 0), 1023);
        atomicAdd(&counts[(ix0 << 10) + iy0], 1u);
        atomicAdd(&counts[(ix1 << 10) + iy1], 1u);
    }
    if (idx == 0 && (nagents & 1)) {
        const float* t = (const float*)pos;
        int ix = min(max((int)(t[2 * (nagents - 1)] * 1024.0f), 0), 1023);
        int iy = min(max((int)(t[2 * (nagents - 1) + 1] * 1024.0f), 0), 1023);
        atomicAdd(&counts[(ix << 10) + iy], 1u);
    }
}

__global__ __launch_bounds__(256) void max_kernel(
    const uint4* __restrict__ counts, unsigned int* __restrict__ out_max)
{
    int idx = blockIdx.x * blockDim.x + threadIdx.x;
    int stride = gridDim.x * blockDim.x;
    unsigned int m = 0;
    const int n4 = (RES * RES) / 4;
    for (int i = idx; i < n4; i += stride) {
        uint4 c = counts[i];
        m = max(m, max(max(c.x, c.y), max(c.z, c.w)));
    }
    #pragma unroll
    for (int off = 32; off > 0; off >>= 1)
        m = max(m, (unsigned int)__shfl_down((int)m, off, 64));
    __shared__ unsigned int sm[4];
    if ((threadIdx.x & 63) == 0) sm[threadIdx.x >> 6] = m;
    __syncthreads();
    if (threadIdx.x == 0) {
        m = max(max(sm[0], sm[1]), max(sm[2], sm[3]));
        atomicMax(out_max, m);
    }
}

__global__ __launch_bounds__(256) void final_full_kernel(
    const float* __restrict__ room_params,
    const float4* __restrict__ wall,
    float4* __restrict__ dyn,
    float* __restrict__ flow,
    const unsigned int* __restrict__ maxp)
{
    int idx = blockIdx.x * blockDim.x + threadIdx.x;   // 0 .. 262143
    uint4 c = ((const uint4*)flow)[idx];
    float inv = 1.0f / ((float)(*maxp) + 1e-6f);
    ((float4*)flow)[idx] = make_float4((float)c.x * inv, (float)c.y * inv,
                                       (float)c.z * inv, (float)c.w * inv);
    dyn_cell(room_params, wall, dyn, idx);
}

extern "C" void kernel_launch(void* const* d_in, const int* in_sizes, int n_in,
                              void* d_out, int out_size, void* d_ws, size_t ws_size,
                              hipStream_t stream) {
    const float* agents      = (const float*)d_in[0];  // (N,2)
    const float* room_params = (const float*)d_in[1];  // (8,4)
    const float* wall        = (const float*)d_in[2];  // (1024,1024)

    float* dyn  = (float*)d_out;
    float* flow = (float*)d_out + (size_t)NROOMS * RES * RES;
    unsigned int* counts = (unsigned int*)flow;

    int nagents = in_sizes[0] / 2;
    int n4 = nagents / 2;

    // ws layout: [0,1024) cursors, [1024,1028) max, [2048, 2048+16MB) buf
    size_t need = 2048 + (size_t)NBUCKETS * CAP * sizeof(unsigned short);

    // main path requires the per-block agent range to fit F4PT float4/thread
    bool fits = ((n4 + NBLK - 1) / NBLK) <= (F4PT * 512);

    if (ws_size >= need && fits) {
        unsigned int*   cursor = (unsigned int*)d_ws;
        unsigned int*   maxp   = (unsigned int*)((char*)d_ws + 1024);
        unsigned short* buf    = (unsigned short*)((char*)d_ws + 2048);

        (void)hipMemsetAsync(d_ws, 0, 2048, stream);           // cursors + max
        scatter_kernel<<<NBLK, 512, 0, stream>>>(
            (const float4*)agents, n4, nagents, buf, cursor,
            room_params, (const float4*)wall, (float4*)dyn);
        hist_build_kernel<<<NBUCKETS, 1024, 0, stream>>>(buf, cursor, counts, maxp);
        norm_kernel<<<(RES * RES / 4) / 256, 256, 0, stream>>>(flow, maxp);
    } else {
        unsigned int* maxp = (unsigned int*)d_ws;
        (void)hipMemsetAsync(flow, 0, (size_t)RES * RES * sizeof(float), stream);
        (void)hipMemsetAsync(maxp, 0, sizeof(unsigned int), stream);
        hist_atomic_kernel<<<1280, 256, 0, stream>>>((const float4*)agents, n4, nagents, counts);
        max_kernel<<<256, 256, 0, stream>>>((const uint4*)counts, maxp);
        final_full_kernel<<<(RES * RES / 4) / 256, 256, 0, stream>>>(
            room_params, (const float4*)wall, (float4*)dyn, flow, maxp);
    }
}